// Round 16
// baseline (147.740 us; speedup 1.0000x reference)
//
#include <hip/hip_runtime.h>
#include <hip/hip_bf16.h>
#include <cstdint>

#define BATCH 4096
#define INF   1024
#define OUTF  1024
#define LCH   12
#define KTOT  (INF*LCH)       // 12288
#define BM    256
#define BN    128
#define BK    48              // 4 features per K-tile
#define NT    64              // K-tiles per k-quarter
#define THREADS 512
#define ASZ   (6*256*8)       // 12288 us = 24 KB per A buffer
#define BSZ   (6*128*8)       // 6144 us  = 12 KB per B buffer

#define WTT_BYTES ((size_t)OUTF * KTOT * 2)            // 25165824
#define PART_FLOATS ((size_t)BATCH * OUTF)             // 4194304
#define PQ_U32   (PART_FLOATS / 2)                     // 2097152 u32 per quarter
#define P_BYTES  ((size_t)4 * PQ_U32 * 4)              // 33554432
#define OUT_BYTES (PART_FLOATS * 4)                    // 16777216

typedef __bf16 bf16x8 __attribute__((ext_vector_type(8)));
typedef float  f32x16 __attribute__((ext_vector_type(16)));
typedef unsigned long long ull;
typedef unsigned short us;

struct alignas(16) U2 { ull x, y; };

__device__ __forceinline__ us f2bf(float f) {
  unsigned int u = __builtin_bit_cast(unsigned int, f);
  u += 0x7FFFu + ((u >> 16) & 1u);
  return (us)(u >> 16);
}

__device__ __forceinline__ void async_copy16(const void* g, void* l) {
  __builtin_amdgcn_global_load_lds(
      (const __attribute__((address_space(1))) unsigned int*)g,
      (__attribute__((address_space(3))) unsigned int*)l,
      16, 0, 0);
}

// double-buffer barrier: drain ALL DMAs (this iter's stage for the next tile)
// + all LDS ops; keep only the newest VMEM (the x prefetch) in flight.
#define PIPE_BARRIER() do {                                        \
  asm volatile("s_waitcnt vmcnt(1) lgkmcnt(0)" ::: "memory");      \
  __builtin_amdgcn_sched_barrier(0);                               \
  __builtin_amdgcn_s_barrier();                                    \
  __builtin_amdgcn_sched_barrier(0);                               \
} while (0)

// 12 bf16 channels (11 spline + base/x) for one feature value (scalar path)
__device__ __forceinline__ void basis12(float xx, ull W[3]) {
  float u  = fmaf(xx, 4.0f, 7.0f);       // in (3,11); x in (-1,1)
  float fm = floorf(u);
  int   mi = (int)fm;                    // 3..10
  float t  = u - fm;
  float s  = 1.0f - t;
  float t2 = t * t, t3 = t2 * t;
  float w0 = (s * s * s) * (1.0f / 6.0f);
  float w3 = t3 * (1.0f / 6.0f);
  float w1 = fmaf(0.5f, t3, 2.0f / 3.0f) - t2;
  float w2 = 1.0f - w0 - w1 - w3;
  int ls = mi - 3;                       // 0..7
  ull W64 = (ull)f2bf(w0)
          | ((ull)f2bf(w1) << 16)
          | ((ull)f2bf(w2) << 32)
          | ((ull)f2bf(w3) << 48);
  int sh = ls << 4;                      // 0..112
  int a  = sh & 63;
  ull lop  = W64 << a;
  ull hip_ = a ? (W64 >> (64 - a)) : 0ull;
  W[0] = (sh < 64) ? lop : 0ull;
  W[1] = (sh < 64) ? hip_ : lop;
  W[2] = ((sh < 64) ? 0ull : hip_) | ((ull)f2bf(xx) << 48); // slot 11 = x
}

// ---- kernel 1: weights -> tiled WtT[bn8][ktG256][gran6][col128][8] bf16 -----
__global__ __launch_bounds__(256) void kan_build_wtT(
    const float* __restrict__ sw,        // [OUTF][INF][11]
    const float* __restrict__ bw,        // [OUTF][INF]
    us* __restrict__ WtT)
{
  int t   = blockIdx.x * 256 + threadIdx.x;   // 0..524287
  int col = t & 127;
  int q   = t >> 7;                           // 0..4095
  int fp  = q & 1;                            // feature pair in tile
  int ktG = (q >> 1) & 255;                   // global K-tile (4 feats)
  int bn  = q >> 9;                           // 0..7
  int o   = bn * 128 + col;
  int i0  = ktG * 4 + fp * 2;                 // even -> 8B-aligned f32 rows

  const float2* s2 = reinterpret_cast<const float2*>(
      sw + (size_t)(o * 1024 + i0) * 11);
  float2 sv[11];
#pragma unroll
  for (int l = 0; l < 11; ++l) sv[l] = s2[l];
  float2 bv = *reinterpret_cast<const float2*>(bw + (size_t)o * 1024 + i0);

  us v[24];
#pragma unroll
  for (int l = 0; l < 11; ++l) {
    int m0 = l;
    int m1 = 11 + l;
    float f0 = (m0 & 1) ? sv[m0 >> 1].y : sv[m0 >> 1].x;
    float f1 = (m1 & 1) ? sv[m1 >> 1].y : sv[m1 >> 1].x;
    v[l]      = f2bf(f0);
    v[12 + l] = f2bf(f1);
  }
  v[11] = f2bf(bv.x);
  v[23] = f2bf(bv.y);

  int g0 = fp * 3;
  us* base = WtT + (size_t)(bn * 256 + ktG) * (6 * 128 * 8);
  U2* p = reinterpret_cast<U2*>(base);
#pragma unroll
  for (int j = 0; j < 3; ++j) {
    U2 u;
    const us* w = v + j * 8;
    u.x = (ull)w[0] | ((ull)w[1] << 16) | ((ull)w[2] << 32) | ((ull)w[3] << 48);
    u.y = (ull)w[4] | ((ull)w[5] << 16) | ((ull)w[6] << 32) | ((ull)w[7] << 48);
    p[(g0 + j) * 128 + col] = u;
  }
}

// basis for 2 features -> 6 named 64-bit words (all-static, cvt_pk packed)
#define BASIS2(XV, W0_,W1_,W2_,W3_,W4_,W5_) do {                         \
  {                                                                      \
    float xx = (XV).x;                                                   \
    float u_  = fmaf(xx, 4.0f, 7.0f);                                    \
    float fm_ = floorf(u_);                                              \
    int   mi_ = (int)fm_;                                                \
    float t_  = u_ - fm_;                                                \
    float s_  = 1.0f - t_;                                               \
    float t2_ = t_ * t_, t3_ = t2_ * t_;                                 \
    float w0_ = (s_ * s_ * s_) * (1.0f / 6.0f);                          \
    float w3_ = t3_ * (1.0f / 6.0f);                                     \
    float w1_ = fmaf(0.5f, t3_, 2.0f / 3.0f) - t2_;                      \
    float w2_ = 1.0f - w0_ - w1_ - w3_;                                  \
    unsigned int p01_, p23_;                                             \
    asm("v_cvt_pk_bf16_f32 %0, %1, %2" : "=v"(p01_) : "v"(w0_), "v"(w1_)); \
    asm("v_cvt_pk_bf16_f32 %0, %1, %2" : "=v"(p23_) : "v"(w2_), "v"(w3_)); \
    ull W64_ = (ull)p01_ | ((ull)p23_ << 32);                            \
    int sh_ = (mi_ - 3) << 4;                                            \
    int a_  = sh_ & 63;                                                  \
    ull lo_ = W64_ << a_;                                                \
    ull hi_ = a_ ? (W64_ >> (64 - a_)) : 0ull;                           \
    W0_ = (sh_ < 64) ? lo_ : 0ull;                                       \
    W1_ = (sh_ < 64) ? hi_ : lo_;                                        \
    W2_ = ((sh_ < 64) ? 0ull : hi_) | ((ull)f2bf(xx) << 48);             \
  }                                                                      \
  {                                                                      \
    float xx = (XV).y;                                                   \
    float u_  = fmaf(xx, 4.0f, 7.0f);                                    \
    float fm_ = floorf(u_);                                              \
    int   mi_ = (int)fm_;                                                \
    float t_  = u_ - fm_;                                                \
    float s_  = 1.0f - t_;                                               \
    float t2_ = t_ * t_, t3_ = t2_ * t_;                                 \
    float w0_ = (s_ * s_ * s_) * (1.0f / 6.0f);                          \
    float w3_ = t3_ * (1.0f / 6.0f);                                     \
    float w1_ = fmaf(0.5f, t3_, 2.0f / 3.0f) - t2_;                      \
    float w2_ = 1.0f - w0_ - w1_ - w3_;                                  \
    unsigned int p01_, p23_;                                             \
    asm("v_cvt_pk_bf16_f32 %0, %1, %2" : "=v"(p01_) : "v"(w0_), "v"(w1_)); \
    asm("v_cvt_pk_bf16_f32 %0, %1, %2" : "=v"(p23_) : "v"(w2_), "v"(w3_)); \
    ull W64_ = (ull)p01_ | ((ull)p23_ << 32);                            \
    int sh_ = (mi_ - 3) << 4;                                            \
    int a_  = sh_ & 63;                                                  \
    ull lo_ = W64_ << a_;                                                \
    ull hi_ = a_ ? (W64_ >> (64 - a_)) : 0ull;                           \
    W3_ = (sh_ < 64) ? lo_ : 0ull;                                       \
    W4_ = (sh_ < 64) ? hi_ : lo_;                                        \
    W5_ = ((sh_ < 64) ? 0ull : hi_) | ((ull)f2bf(xx) << 48);             \
  }                                                                      \
} while (0)

// ---- kernel 2: fused GEMM, 256x128 tile, k-quarter split, 64x64 waves -------
// 72 KB LDS -> 2 blocks/CU -> 4 waves/SIMD. R15 + T5 setprio around MFMA
// (independent unsynced blocks per CU = the regime where setprio pays).
__global__ __launch_bounds__(THREADS, 4) void kan_gemm(
    const float* __restrict__ x,             // [BATCH][INF]
    const us* __restrict__ WtT,              // tiled B
    unsigned int* __restrict__ P)            // packed-bf16 partials [4][4096][512]
{
  __shared__ alignas(16) us smem[2 * ASZ + 2 * BSZ];   // 73728 B

  const int tid  = threadIdx.x;
  const int lane = tid & 63;
  const int wid  = tid >> 6;              // 0..7
  const int wm   = (wid >> 1) * 64;       // 4 row groups of 64
  const int wn   = (wid & 1) * 64;        // 2 col groups of 64
  const int lo   = lane & 31;
  const int lh   = lane >> 5;
  const int b    = (int)blockIdx.x;       // 0..511
  const int bn   = b & 7;                 // panel == XCD id under RR dispatch
  const int kq   = (b >> 3) & 3;          // k-quarter
  const int bm   = b >> 5;                // 0..15

  const int r   = tid & 255;
  const int fp  = tid >> 8;               // 0 or 1
  const int g0A = fp * 3;
  const float* xrow = x + (size_t)(bm * BM + r) * INF + kq * 256 + fp * 2;

  us* Acur = smem;
  us* Aalt = smem + ASZ;
  us* Bcur = smem + 2 * ASZ;
  us* Balt = smem + 2 * ASZ + BSZ;

  f32x16 acc[2][2] = {};

  auto stageB = [&](int c, us* Bd) {
    if (wid < 6) {
      const int ktG = kq * NT + c;
      const us* base = WtT + (size_t)(bn * 256 + ktG) * (6 * 128 * 8);
#pragma unroll
      for (int j = 0; j < 2; ++j) {
        int ch = wid * 2 + j;             // 0..11
        int g = ch >> 1, h = ch & 1;
        async_copy16(base + g * 1024 + h * 512 + lane * 8,
                     Bd + g * 1024 + h * 512);   // wave-uniform dest
      }
    }
  };

#define WRITEW(AD, W0_,W1_,W2_,W3_,W4_,W5_) do {                   \
    U2* p_ = reinterpret_cast<U2*>(AD);                            \
    U2 u0_; u0_.x = W0_; u0_.y = W1_;                              \
    U2 u1_; u1_.x = W2_; u1_.y = W3_;                              \
    U2 u2_; u2_.x = W4_; u2_.y = W5_;                              \
    p_[(g0A + 0) * 256 + r] = u0_;                                 \
    p_[(g0A + 1) * 256 + r] = u1_;                                 \
    p_[(g0A + 2) * 256 + r] = u2_;                                 \
  } while (0)

#define READK(S, A0,A1,B0,B1) do {                                 \
    const int kk_ = (S) * 2 + lh;                                  \
    A0 = *reinterpret_cast<const bf16x8*>(&Acur[(kk_ * 256 + wm +  0 + lo) * 8]); \
    A1 = *reinterpret_cast<const bf16x8*>(&Acur[(kk_ * 256 + wm + 32 + lo) * 8]); \
    B0 = *reinterpret_cast<const bf16x8*>(&Bcur[(kk_ * 128 + wn +  0 + lo) * 8]); \
    B1 = *reinterpret_cast<const bf16x8*>(&Bcur[(kk_ * 128 + wn + 32 + lo) * 8]); \
  } while (0)

#define MFMAK(A0,A1,B0,B1) do {                                    \
    __builtin_amdgcn_s_setprio(1);                                 \
    acc[0][0] = __builtin_amdgcn_mfma_f32_32x32x16_bf16(A0, B0, acc[0][0], 0, 0, 0); \
    acc[0][1] = __builtin_amdgcn_mfma_f32_32x32x16_bf16(A0, B1, acc[0][1], 0, 0, 0); \
    acc[1][0] = __builtin_amdgcn_mfma_f32_32x32x16_bf16(A1, B0, acc[1][0], 0, 0, 0); \
    acc[1][1] = __builtin_amdgcn_mfma_f32_32x32x16_bf16(A1, B1, acc[1][1], 0, 0, 0); \
    __builtin_amdgcn_s_setprio(0);                                 \
  } while (0)

  // ---- prologue: DMAs first, x prefetch LAST (vmcnt(1) keeps it) ----
  stageB(0, Bcur);
  {
    float2 x0 = *reinterpret_cast<const float2*>(xrow);
    ull W0, W1, W2, W3, W4, W5;
    BASIS2(x0, W0, W1, W2, W3, W4, W5);
    WRITEW(Acur, W0, W1, W2, W3, W4, W5);
  }
  float2 xa = *reinterpret_cast<const float2*>(xrow + 4); // newest VMEM
  PIPE_BARRIER();

  for (int c = 0; c < NT; ++c) {
    const int cf = (c + 2 < NT) ? (c + 2) : (NT - 1);

    stageB(c + 1 < NT ? c + 1 : NT - 1, Balt);                     // DMAs first
    float2 xb = *reinterpret_cast<const float2*>(xrow + cf * 4);   // newest VMEM

    ull W0, W1, W2, W3, W4, W5;
    bf16x8 a00, a01, b00, b01;
    bf16x8 a10, a11, b10, b11;
    bf16x8 a20, a21, b20, b21;

    READK(0, a00, a01, b00, b01);
    BASIS2(xa, W0, W1, W2, W3, W4, W5);       // VALU under read-0 latency
    READK(1, a10, a11, b10, b11);
    MFMAK(a00, a01, b00, b01);
    READK(2, a20, a21, b20, b21);
    MFMAK(a10, a11, b10, b11);
    __builtin_amdgcn_sched_barrier(0);        // pin: all reads precede writes
    WRITEW(Aalt, W0, W1, W2, W3, W4, W5);
    MFMAK(a20, a21, b20, b21);

    PIPE_BARRIER();

    us* t = Bcur; Bcur = Balt; Balt = t;
    t = Acur; Acur = Aalt; Aalt = t;
    xa = xb;
  }

  asm volatile("s_waitcnt vmcnt(0) lgkmcnt(0)" ::: "memory");

  // ---- epilogue: pack col-pair (wn+lo, wn+32+lo); u = bn*64 + (wn>>1) + lo --
  unsigned int* dst = P + (size_t)kq * PQ_U32;
  const int ubase = bn * 64 + (wn >> 1) + lo;
#pragma unroll
  for (int f = 0; f < 2; ++f) {
#pragma unroll
    for (int rr = 0; rr < 16; ++rr) {
      int row = bm * BM + wm + f * 32 + (rr & 3) + 8 * (rr >> 2) + 4 * lh;
      unsigned int pk;
      asm("v_cvt_pk_bf16_f32 %0, %1, %2"
          : "=v"(pk) : "v"(acc[f][0][rr]), "v"(acc[f][1][rr]));
      dst[(size_t)row * 512 + ubase] = pk;
    }
  }
}

// ---- kernel 3: unpack 4 bf16-packed partials, fixed-order sum -> f32 out ----
__global__ __launch_bounds__(256) void kan_reduce4p(
    float* __restrict__ out, const uint4* __restrict__ P)
{
  size_t i = (size_t)blockIdx.x * 256 + threadIdx.x;   // 0..524287
  const size_t Q = PQ_U32 / 4;
  uint4 a = P[i], b = P[i + Q], c = P[i + 2 * Q], d = P[i + 3 * Q];

  size_t u0  = i * 4;
  size_t row = u0 >> 9;
  int ur   = (int)(u0 & 511);
  int col0 = (ur >> 6) * 128 + ((ur >> 5) & 1) * 64 + (ur & 31);

  float4 vlo, vhi;
  {
    unsigned int ua[4] = {a.x, a.y, a.z, a.w};
    unsigned int ub[4] = {b.x, b.y, b.z, b.w};
    unsigned int uc[4] = {c.x, c.y, c.z, c.w};
    unsigned int ud[4] = {d.x, d.y, d.z, d.w};
    float* plo = &vlo.x;
    float* phi = &vhi.x;
#pragma unroll
    for (int j = 0; j < 4; ++j) {
      float la = __builtin_bit_cast(float, ua[j] << 16);
      float lb = __builtin_bit_cast(float, ub[j] << 16);
      float lc = __builtin_bit_cast(float, uc[j] << 16);
      float ld = __builtin_bit_cast(float, ud[j] << 16);
      float ha = __builtin_bit_cast(float, ua[j] & 0xffff0000u);
      float hb = __builtin_bit_cast(float, ub[j] & 0xffff0000u);
      float hc = __builtin_bit_cast(float, uc[j] & 0xffff0000u);
      float hd = __builtin_bit_cast(float, ud[j] & 0xffff0000u);
      plo[j] = (la + lb) + (lc + ld);   // fixed order -> deterministic
      phi[j] = (ha + hb) + (hc + hd);
    }
  }
  *reinterpret_cast<float4*>(out + row * 1024 + col0)      = vlo;
  *reinterpret_cast<float4*>(out + row * 1024 + col0 + 32) = vhi;
}

// ======================= fallback path (R8-class, proven) ====================
#define FB_BUFSZ (6*128*8)

__global__ __launch_bounds__(256) void kan_build_wt(
    const float* __restrict__ sw, const float* __restrict__ bw,
    us* __restrict__ Wt)
{
  int idx = blockIdx.x * 256 + threadIdx.x;
  int o = idx >> 10;
  int i = idx & 1023;
  const float* s = sw + (size_t)(o * 1024 + i) * 11;
  us v[12];
#pragma unroll
  for (int l = 0; l < 11; ++l) v[l] = f2bf(s[l]);
  v[11] = f2bf(bw[o * 1024 + i]);
  us* d = Wt + (size_t)o * KTOT + i * 12;
  *reinterpret_cast<ushort4*>(d + 0) = make_ushort4(v[0], v[1], v[2],  v[3]);
  *reinterpret_cast<ushort4*>(d + 4) = make_ushort4(v[4], v[5], v[6],  v[7]);
  *reinterpret_cast<ushort4*>(d + 8) = make_ushort4(v[8], v[9], v[10], v[11]);
}

__global__ __launch_bounds__(512, 4) void kan_gemm_fb(
    const float* __restrict__ x, const us* __restrict__ Wt,
    float* __restrict__ out)
{
  __shared__ alignas(16) us smem[5 * FB_BUFSZ];
  const int tid  = threadIdx.x;
  const int lane = tid & 63;
  const int wid  = tid >> 6;
  const int wm   = (wid >> 2) * 64;
  const int wn   = (wid & 3) * 32;
  const int lo   = lane & 31;
  const int lh   = lane >> 5;
  const int idx  = (int)blockIdx.x;
  const int bn   = idx & 7;
  const int kh   = (idx >> 3) & 1;
  const int bm   = idx >> 4;
  const bool builder = (tid < 256);
  const bool stager  = (wid >= 4);
  const int ab  = tid & 127;
  const int ai0 = ((tid >> 7) & 1) << 1;
  const float* xrow = x + (size_t)(bm * 128 + ab) * INF + kh * 512 + ai0;
  const size_t kbase = (size_t)kh * (KTOT / 2);

  us* Bcur = smem;            us* Bnxt = smem + FB_BUFSZ;
  us* Bnn  = smem + 2 * FB_BUFSZ;
  us* Acur = smem + 3 * FB_BUFSZ; us* Aalt = smem + 4 * FB_BUFSZ;
  f32x16 acc[2] = {};

  auto stageB = [&](int c, us* Bd) {
    const int wq = wid - 4;
#pragma unroll
    for (int qq = 0; qq < 3; ++qq) {
      int G  = (wq * 3 + qq) * 64 + lane;
      int kk = G >> 7;
      int oo = G & 127;
      const us* src = Wt + (size_t)(bn * 128 + oo) * KTOT + kbase + c * 48 + kk * 8;
      async_copy16(src, Bd + (wq * 3 + qq) * 512);
    }
  };
  auto buildA = [&](float2 xv, us* Ad) {
    ull W[6];
    basis12(xv.x, W + 0);
    basis12(xv.y, W + 3);
    U2* p = reinterpret_cast<U2*>(Ad);
    const int g0 = (ai0 >> 1) * 3;
    U2 u0; u0.x = W[0]; u0.y = W[1];
    U2 u1; u1.x = W[2]; u1.y = W[3];
    U2 u2; u2.x = W[4]; u2.y = W[5];
    p[(g0 + 0) * 128 + ab] = u0;
    p[(g0 + 1) * 128 + ab] = u1;
    p[(g0 + 2) * 128 + ab] = u2;
  };

  float2 xa = make_float2(0.f, 0.f);
  if (builder) {
    float2 x0v = *reinterpret_cast<const float2*>(xrow);
    buildA(x0v, Acur);
    xa = *reinterpret_cast<const float2*>(xrow + 4);
  }
  if (stager) { stageB(0, Bcur); stageB(1, Bnxt); }
  asm volatile("s_waitcnt vmcnt(3) lgkmcnt(0)" ::: "memory");
  __builtin_amdgcn_s_barrier();

  for (int c = 0; c < 128; ++c) {
    int cf = (c + 2 < 128) ? (c + 2) : 127;
    float2 xb = xa;
    if (builder) {
      xb = *reinterpret_cast<const float2*>(xrow + cf * 4);
      buildA(xa, Aalt);
    }
    if (stager) stageB(cf, Bnn);
#pragma unroll
    for (int s = 0; s < 3; ++s) {
      const int kk = s * 2 + lh;
      bf16x8 a0 = *reinterpret_cast<const bf16x8*>(&Acur[(kk * 128 + wm + lo) * 8]);
      bf16x8 a1 = *reinterpret_cast<const bf16x8*>(&Acur[(kk * 128 + wm + 32 + lo) * 8]);
      bf16x8 b0 = *reinterpret_cast<const bf16x8*>(&Bcur[(kk * 128 + wn + lo) * 8]);
      acc[0] = __builtin_amdgcn_mfma_f32_32x32x16_bf16(a0, b0, acc[0], 0, 0, 0);
      acc[1] = __builtin_amdgcn_mfma_f32_32x32x16_bf16(a1, b0, acc[1], 0, 0, 0);
    }
    asm volatile("s_waitcnt vmcnt(3) lgkmcnt(0)" ::: "memory");
    __builtin_amdgcn_s_barrier();
    us* t = Bcur; Bcur = Bnxt; Bnxt = Bnn; Bnn = t;
    t = Acur; Acur = Aalt; Aalt = t;
    xa = xb;
  }
  asm volatile("s_waitcnt vmcnt(0) lgkmcnt(0)" ::: "memory");
#pragma unroll
  for (int mf = 0; mf < 2; ++mf)
#pragma unroll
    for (int r2 = 0; r2 < 16; ++r2) {
      int row = bm * 128 + wm + mf * 32 + (r2 & 3) + 8 * (r2 >> 2) + 4 * lh;
      atomicAdd(out + (size_t)row * OUTF + bn * 128 + wn + lo, acc[mf][r2]);
    }
}

// =============================================================================
extern "C" void kernel_launch(void* const* d_in, const int* in_sizes, int n_in,
                              void* d_out, int out_size, void* d_ws, size_t ws_size,
                              hipStream_t stream) {
  const float* x  = (const float*)d_in[0];   // [4096][1024]
  const float* bw = (const float*)d_in[1];   // [1024][1024]
  const float* sw = (const float*)d_in[2];   // [1024][1024][11]
  float* out = (float*)d_out;

  if (ws_size >= WTT_BYTES + P_BYTES) {
    us* WtT = (us*)d_ws;
    unsigned int* P = (unsigned int*)((char*)d_ws + WTT_BYTES);
    kan_build_wtT<<<2048, 256, 0, stream>>>(sw, bw, WtT);
    kan_gemm<<<512, THREADS, 0, stream>>>(x, WtT, P);
    kan_reduce4p<<<(int)(PQ_U32 / 4 / 256), 256, 0, stream>>>(
        out, (const uint4*)P);
  } else if (ws_size >= WTT_BYTES) {
    us* Wt = (us*)d_ws;
    kan_build_wt<<<(OUTF * INF) / 256, 256, 0, stream>>>(sw, bw, Wt);
    hipMemsetAsync(d_out, 0, OUT_BYTES, stream);
    kan_gemm_fb<<<512, 512, 0, stream>>>(x, Wt, out);
  }
}

// Round 17
// 140.682 us; speedup vs baseline: 1.0502x; 1.0502x over previous
//
#include <hip/hip_runtime.h>
#include <hip/hip_bf16.h>
#include <cstdint>

#define BATCH 4096
#define INF   1024
#define OUTF  1024
#define LCH   12
#define KTOT  (INF*LCH)       // 12288
#define BM    256
#define BN    128
#define BK    48              // 4 features per K-tile
#define NT    64              // K-tiles per k-quarter
#define THREADS 512
#define ASZ   (6*256*8)       // 12288 us = 24 KB per A buffer
#define BSZ   (6*128*8)       // 6144 us  = 12 KB per B buffer

#define WTT_BYTES ((size_t)OUTF * KTOT * 2)            // 25165824
#define PART_FLOATS ((size_t)BATCH * OUTF)             // 4194304
#define PQ_U32   (PART_FLOATS / 2)                     // 2097152 u32 per quarter
#define P_BYTES  ((size_t)4 * PQ_U32 * 4)              // 33554432
#define OUT_BYTES (PART_FLOATS * 4)                    // 16777216

typedef __bf16 bf16x8 __attribute__((ext_vector_type(8)));
typedef float  f32x16 __attribute__((ext_vector_type(16)));
typedef unsigned long long ull;
typedef unsigned short us;

struct alignas(16) U2 { ull x, y; };

__device__ __forceinline__ us f2bf(float f) {
  unsigned int u = __builtin_bit_cast(unsigned int, f);
  u += 0x7FFFu + ((u >> 16) & 1u);
  return (us)(u >> 16);
}

__device__ __forceinline__ void async_copy16(const void* g, void* l) {
  __builtin_amdgcn_global_load_lds(
      (const __attribute__((address_space(1))) unsigned int*)g,
      (__attribute__((address_space(3))) unsigned int*)l,
      16, 0, 0);
}

// double-buffer barrier: drain ALL DMAs (this iter's stage for the next tile)
// + all LDS ops; keep only the newest VMEM (the x prefetch) in flight.
#define PIPE_BARRIER() do {                                        \
  asm volatile("s_waitcnt vmcnt(1) lgkmcnt(0)" ::: "memory");      \
  __builtin_amdgcn_sched_barrier(0);                               \
  __builtin_amdgcn_s_barrier();                                    \
  __builtin_amdgcn_sched_barrier(0);                               \
} while (0)

// 12 bf16 channels (11 spline + base/x) for one feature value (scalar path)
__device__ __forceinline__ void basis12(float xx, ull W[3]) {
  float u  = fmaf(xx, 4.0f, 7.0f);       // in (3,11); x in (-1,1)
  float fm = floorf(u);
  int   mi = (int)fm;                    // 3..10
  float t  = u - fm;
  float s  = 1.0f - t;
  float t2 = t * t, t3 = t2 * t;
  float w0 = (s * s * s) * (1.0f / 6.0f);
  float w3 = t3 * (1.0f / 6.0f);
  float w1 = fmaf(0.5f, t3, 2.0f / 3.0f) - t2;
  float w2 = 1.0f - w0 - w1 - w3;
  int ls = mi - 3;                       // 0..7
  ull W64 = (ull)f2bf(w0)
          | ((ull)f2bf(w1) << 16)
          | ((ull)f2bf(w2) << 32)
          | ((ull)f2bf(w3) << 48);
  int sh = ls << 4;                      // 0..112
  int a  = sh & 63;
  ull lop  = W64 << a;
  ull hip_ = a ? (W64 >> (64 - a)) : 0ull;
  W[0] = (sh < 64) ? lop : 0ull;
  W[1] = (sh < 64) ? hip_ : lop;
  W[2] = ((sh < 64) ? 0ull : hip_) | ((ull)f2bf(xx) << 48); // slot 11 = x
}

// ---- kernel 1: weights -> tiled WtT[bn8][ktG256][gran6][col128][8] bf16 -----
__global__ __launch_bounds__(256) void kan_build_wtT(
    const float* __restrict__ sw,        // [OUTF][INF][11]
    const float* __restrict__ bw,        // [OUTF][INF]
    us* __restrict__ WtT)
{
  int t   = blockIdx.x * 256 + threadIdx.x;   // 0..524287
  int col = t & 127;
  int q   = t >> 7;                           // 0..4095
  int fp  = q & 1;                            // feature pair in tile
  int ktG = (q >> 1) & 255;                   // global K-tile (4 feats)
  int bn  = q >> 9;                           // 0..7
  int o   = bn * 128 + col;
  int i0  = ktG * 4 + fp * 2;                 // even -> 8B-aligned f32 rows

  const float2* s2 = reinterpret_cast<const float2*>(
      sw + (size_t)(o * 1024 + i0) * 11);
  float2 sv[11];
#pragma unroll
  for (int l = 0; l < 11; ++l) sv[l] = s2[l];
  float2 bv = *reinterpret_cast<const float2*>(bw + (size_t)o * 1024 + i0);

  us v[24];
#pragma unroll
  for (int l = 0; l < 11; ++l) {
    int m0 = l;
    int m1 = 11 + l;
    float f0 = (m0 & 1) ? sv[m0 >> 1].y : sv[m0 >> 1].x;
    float f1 = (m1 & 1) ? sv[m1 >> 1].y : sv[m1 >> 1].x;
    v[l]      = f2bf(f0);
    v[12 + l] = f2bf(f1);
  }
  v[11] = f2bf(bv.x);
  v[23] = f2bf(bv.y);

  int g0 = fp * 3;
  us* base = WtT + (size_t)(bn * 256 + ktG) * (6 * 128 * 8);
  U2* p = reinterpret_cast<U2*>(base);
#pragma unroll
  for (int j = 0; j < 3; ++j) {
    U2 u;
    const us* w = v + j * 8;
    u.x = (ull)w[0] | ((ull)w[1] << 16) | ((ull)w[2] << 32) | ((ull)w[3] << 48);
    u.y = (ull)w[4] | ((ull)w[5] << 16) | ((ull)w[6] << 32) | ((ull)w[7] << 48);
    p[(g0 + j) * 128 + col] = u;
  }
}

// basis for 2 features -> 6 named 64-bit words (all-static, cvt_pk packed)
#define BASIS2(XV, W0_,W1_,W2_,W3_,W4_,W5_) do {                         \
  {                                                                      \
    float xx = (XV).x;                                                   \
    float u_  = fmaf(xx, 4.0f, 7.0f);                                    \
    float fm_ = floorf(u_);                                              \
    int   mi_ = (int)fm_;                                                \
    float t_  = u_ - fm_;                                                \
    float s_  = 1.0f - t_;                                               \
    float t2_ = t_ * t_, t3_ = t2_ * t_;                                 \
    float w0_ = (s_ * s_ * s_) * (1.0f / 6.0f);                          \
    float w3_ = t3_ * (1.0f / 6.0f);                                     \
    float w1_ = fmaf(0.5f, t3_, 2.0f / 3.0f) - t2_;                      \
    float w2_ = 1.0f - w0_ - w1_ - w3_;                                  \
    unsigned int p01_, p23_;                                             \
    asm("v_cvt_pk_bf16_f32 %0, %1, %2" : "=v"(p01_) : "v"(w0_), "v"(w1_)); \
    asm("v_cvt_pk_bf16_f32 %0, %1, %2" : "=v"(p23_) : "v"(w2_), "v"(w3_)); \
    ull W64_ = (ull)p01_ | ((ull)p23_ << 32);                            \
    int sh_ = (mi_ - 3) << 4;                                            \
    int a_  = sh_ & 63;                                                  \
    ull lo_ = W64_ << a_;                                                \
    ull hi_ = a_ ? (W64_ >> (64 - a_)) : 0ull;                           \
    W0_ = (sh_ < 64) ? lo_ : 0ull;                                       \
    W1_ = (sh_ < 64) ? hi_ : lo_;                                        \
    W2_ = ((sh_ < 64) ? 0ull : hi_) | ((ull)f2bf(xx) << 48);             \
  }                                                                      \
  {                                                                      \
    float xx = (XV).y;                                                   \
    float u_  = fmaf(xx, 4.0f, 7.0f);                                    \
    float fm_ = floorf(u_);                                              \
    int   mi_ = (int)fm_;                                                \
    float t_  = u_ - fm_;                                                \
    float s_  = 1.0f - t_;                                               \
    float t2_ = t_ * t_, t3_ = t2_ * t_;                                 \
    float w0_ = (s_ * s_ * s_) * (1.0f / 6.0f);                          \
    float w3_ = t3_ * (1.0f / 6.0f);                                     \
    float w1_ = fmaf(0.5f, t3_, 2.0f / 3.0f) - t2_;                      \
    float w2_ = 1.0f - w0_ - w1_ - w3_;                                  \
    unsigned int p01_, p23_;                                             \
    asm("v_cvt_pk_bf16_f32 %0, %1, %2" : "=v"(p01_) : "v"(w0_), "v"(w1_)); \
    asm("v_cvt_pk_bf16_f32 %0, %1, %2" : "=v"(p23_) : "v"(w2_), "v"(w3_)); \
    ull W64_ = (ull)p01_ | ((ull)p23_ << 32);                            \
    int sh_ = (mi_ - 3) << 4;                                            \
    int a_  = sh_ & 63;                                                  \
    ull lo_ = W64_ << a_;                                                \
    ull hi_ = a_ ? (W64_ >> (64 - a_)) : 0ull;                           \
    W3_ = (sh_ < 64) ? lo_ : 0ull;                                       \
    W4_ = (sh_ < 64) ? hi_ : lo_;                                        \
    W5_ = ((sh_ < 64) ? 0ull : hi_) | ((ull)f2bf(xx) << 48);             \
  }                                                                      \
} while (0)

// ---- kernel 2: fused GEMM, 256x128 tile, k-quarter split, 64x64 waves -------
// 72 KB LDS -> 2 blocks/CU -> 4 waves/SIMD (R15 exact; setprio refuted in R16).
__global__ __launch_bounds__(THREADS, 4) void kan_gemm(
    const float* __restrict__ x,             // [BATCH][INF]
    const us* __restrict__ WtT,              // tiled B
    unsigned int* __restrict__ P)            // packed-bf16 partials [4][4096][512]
{
  __shared__ alignas(16) us smem[2 * ASZ + 2 * BSZ];   // 73728 B

  const int tid  = threadIdx.x;
  const int lane = tid & 63;
  const int wid  = tid >> 6;              // 0..7
  const int wm   = (wid >> 1) * 64;       // 4 row groups of 64
  const int wn   = (wid & 1) * 64;        // 2 col groups of 64
  const int lo   = lane & 31;
  const int lh   = lane >> 5;
  const int b    = (int)blockIdx.x;       // 0..511
  const int bn   = b & 7;                 // panel == XCD id under RR dispatch
  const int kq   = (b >> 3) & 3;          // k-quarter
  const int bm   = b >> 5;                // 0..15

  const int r   = tid & 255;
  const int fp  = tid >> 8;               // 0 or 1
  const int g0A = fp * 3;
  const float* xrow = x + (size_t)(bm * BM + r) * INF + kq * 256 + fp * 2;

  us* Acur = smem;
  us* Aalt = smem + ASZ;
  us* Bcur = smem + 2 * ASZ;
  us* Balt = smem + 2 * ASZ + BSZ;

  f32x16 acc[2][2] = {};

  auto stageB = [&](int c, us* Bd) {
    if (wid < 6) {
      const int ktG = kq * NT + c;
      const us* base = WtT + (size_t)(bn * 256 + ktG) * (6 * 128 * 8);
#pragma unroll
      for (int j = 0; j < 2; ++j) {
        int ch = wid * 2 + j;             // 0..11
        int g = ch >> 1, h = ch & 1;
        async_copy16(base + g * 1024 + h * 512 + lane * 8,
                     Bd + g * 1024 + h * 512);   // wave-uniform dest
      }
    }
  };

#define WRITEW(AD, W0_,W1_,W2_,W3_,W4_,W5_) do {                   \
    U2* p_ = reinterpret_cast<U2*>(AD);                            \
    U2 u0_; u0_.x = W0_; u0_.y = W1_;                              \
    U2 u1_; u1_.x = W2_; u1_.y = W3_;                              \
    U2 u2_; u2_.x = W4_; u2_.y = W5_;                              \
    p_[(g0A + 0) * 256 + r] = u0_;                                 \
    p_[(g0A + 1) * 256 + r] = u1_;                                 \
    p_[(g0A + 2) * 256 + r] = u2_;                                 \
  } while (0)

#define READK(S, A0,A1,B0,B1) do {                                 \
    const int kk_ = (S) * 2 + lh;                                  \
    A0 = *reinterpret_cast<const bf16x8*>(&Acur[(kk_ * 256 + wm +  0 + lo) * 8]); \
    A1 = *reinterpret_cast<const bf16x8*>(&Acur[(kk_ * 256 + wm + 32 + lo) * 8]); \
    B0 = *reinterpret_cast<const bf16x8*>(&Bcur[(kk_ * 128 + wn +  0 + lo) * 8]); \
    B1 = *reinterpret_cast<const bf16x8*>(&Bcur[(kk_ * 128 + wn + 32 + lo) * 8]); \
  } while (0)

#define MFMAK(A0,A1,B0,B1) do {                                    \
    acc[0][0] = __builtin_amdgcn_mfma_f32_32x32x16_bf16(A0, B0, acc[0][0], 0, 0, 0); \
    acc[0][1] = __builtin_amdgcn_mfma_f32_32x32x16_bf16(A0, B1, acc[0][1], 0, 0, 0); \
    acc[1][0] = __builtin_amdgcn_mfma_f32_32x32x16_bf16(A1, B0, acc[1][0], 0, 0, 0); \
    acc[1][1] = __builtin_amdgcn_mfma_f32_32x32x16_bf16(A1, B1, acc[1][1], 0, 0, 0); \
  } while (0)

  // ---- prologue: DMAs first, x prefetch LAST (vmcnt(1) keeps it) ----
  stageB(0, Bcur);
  {
    float2 x0 = *reinterpret_cast<const float2*>(xrow);
    ull W0, W1, W2, W3, W4, W5;
    BASIS2(x0, W0, W1, W2, W3, W4, W5);
    WRITEW(Acur, W0, W1, W2, W3, W4, W5);
  }
  float2 xa = *reinterpret_cast<const float2*>(xrow + 4); // newest VMEM
  PIPE_BARRIER();

  for (int c = 0; c < NT; ++c) {
    const int cf = (c + 2 < NT) ? (c + 2) : (NT - 1);

    stageB(c + 1 < NT ? c + 1 : NT - 1, Balt);                     // DMAs first
    float2 xb = *reinterpret_cast<const float2*>(xrow + cf * 4);   // newest VMEM

    ull W0, W1, W2, W3, W4, W5;
    bf16x8 a00, a01, b00, b01;
    bf16x8 a10, a11, b10, b11;
    bf16x8 a20, a21, b20, b21;

    READK(0, a00, a01, b00, b01);
    BASIS2(xa, W0, W1, W2, W3, W4, W5);       // VALU under read-0 latency
    READK(1, a10, a11, b10, b11);
    MFMAK(a00, a01, b00, b01);
    READK(2, a20, a21, b20, b21);
    MFMAK(a10, a11, b10, b11);
    __builtin_amdgcn_sched_barrier(0);        // pin: all reads precede writes
    WRITEW(Aalt, W0, W1, W2, W3, W4, W5);
    MFMAK(a20, a21, b20, b21);

    PIPE_BARRIER();

    us* t = Bcur; Bcur = Balt; Balt = t;
    t = Acur; Acur = Aalt; Aalt = t;
    xa = xb;
  }

  asm volatile("s_waitcnt vmcnt(0) lgkmcnt(0)" ::: "memory");

  // ---- epilogue: pack col-pair (wn+lo, wn+32+lo); u = bn*64 + (wn>>1) + lo --
  unsigned int* dst = P + (size_t)kq * PQ_U32;
  const int ubase = bn * 64 + (wn >> 1) + lo;
#pragma unroll
  for (int f = 0; f < 2; ++f) {
#pragma unroll
    for (int rr = 0; rr < 16; ++rr) {
      int row = bm * BM + wm + f * 32 + (rr & 3) + 8 * (rr >> 2) + 4 * lh;
      unsigned int pk;
      asm("v_cvt_pk_bf16_f32 %0, %1, %2"
          : "=v"(pk) : "v"(acc[f][0][rr]), "v"(acc[f][1][rr]));
      dst[(size_t)row * 512 + ubase] = pk;
    }
  }
}

// ---- kernel 3: unpack 4 bf16-packed partials, fixed-order sum -> f32 out ----
__global__ __launch_bounds__(256) void kan_reduce4p(
    float* __restrict__ out, const uint4* __restrict__ P)
{
  size_t i = (size_t)blockIdx.x * 256 + threadIdx.x;   // 0..524287
  const size_t Q = PQ_U32 / 4;
  uint4 a = P[i], b = P[i + Q], c = P[i + 2 * Q], d = P[i + 3 * Q];

  size_t u0  = i * 4;
  size_t row = u0 >> 9;
  int ur   = (int)(u0 & 511);
  int col0 = (ur >> 6) * 128 + ((ur >> 5) & 1) * 64 + (ur & 31);

  float4 vlo, vhi;
  {
    unsigned int ua[4] = {a.x, a.y, a.z, a.w};
    unsigned int ub[4] = {b.x, b.y, b.z, b.w};
    unsigned int uc[4] = {c.x, c.y, c.z, c.w};
    unsigned int ud[4] = {d.x, d.y, d.z, d.w};
    float* plo = &vlo.x;
    float* phi = &vhi.x;
#pragma unroll
    for (int j = 0; j < 4; ++j) {
      float la = __builtin_bit_cast(float, ua[j] << 16);
      float lb = __builtin_bit_cast(float, ub[j] << 16);
      float lc = __builtin_bit_cast(float, uc[j] << 16);
      float ld = __builtin_bit_cast(float, ud[j] << 16);
      float ha = __builtin_bit_cast(float, ua[j] & 0xffff0000u);
      float hb = __builtin_bit_cast(float, ub[j] & 0xffff0000u);
      float hc = __builtin_bit_cast(float, uc[j] & 0xffff0000u);
      float hd = __builtin_bit_cast(float, ud[j] & 0xffff0000u);
      plo[j] = (la + lb) + (lc + ld);   // fixed order -> deterministic
      phi[j] = (ha + hb) + (hc + hd);
    }
  }
  *reinterpret_cast<float4*>(out + row * 1024 + col0)      = vlo;
  *reinterpret_cast<float4*>(out + row * 1024 + col0 + 32) = vhi;
}

// ======================= fallback path (R8-class, proven) ====================
#define FB_BUFSZ (6*128*8)

__global__ __launch_bounds__(256) void kan_build_wt(
    const float* __restrict__ sw, const float* __restrict__ bw,
    us* __restrict__ Wt)
{
  int idx = blockIdx.x * 256 + threadIdx.x;
  int o = idx >> 10;
  int i = idx & 1023;
  const float* s = sw + (size_t)(o * 1024 + i) * 11;
  us v[12];
#pragma unroll
  for (int l = 0; l < 11; ++l) v[l] = f2bf(s[l]);
  v[11] = f2bf(bw[o * 1024 + i]);
  us* d = Wt + (size_t)o * KTOT + i * 12;
  *reinterpret_cast<ushort4*>(d + 0) = make_ushort4(v[0], v[1], v[2],  v[3]);
  *reinterpret_cast<ushort4*>(d + 4) = make_ushort4(v[4], v[5], v[6],  v[7]);
  *reinterpret_cast<ushort4*>(d + 8) = make_ushort4(v[8], v[9], v[10], v[11]);
}

__global__ __launch_bounds__(512, 4) void kan_gemm_fb(
    const float* __restrict__ x, const us* __restrict__ Wt,
    float* __restrict__ out)
{
  __shared__ alignas(16) us smem[5 * FB_BUFSZ];
  const int tid  = threadIdx.x;
  const int lane = tid & 63;
  const int wid  = tid >> 6;
  const int wm   = (wid >> 2) * 64;
  const int wn   = (wid & 3) * 32;
  const int lo   = lane & 31;
  const int lh   = lane >> 5;
  const int idx  = (int)blockIdx.x;
  const int bn   = idx & 7;
  const int kh   = (idx >> 3) & 1;
  const int bm   = idx >> 4;
  const bool builder = (tid < 256);
  const bool stager  = (wid >= 4);
  const int ab  = tid & 127;
  const int ai0 = ((tid >> 7) & 1) << 1;
  const float* xrow = x + (size_t)(bm * 128 + ab) * INF + kh * 512 + ai0;
  const size_t kbase = (size_t)kh * (KTOT / 2);

  us* Bcur = smem;            us* Bnxt = smem + FB_BUFSZ;
  us* Bnn  = smem + 2 * FB_BUFSZ;
  us* Acur = smem + 3 * FB_BUFSZ; us* Aalt = smem + 4 * FB_BUFSZ;
  f32x16 acc[2] = {};

  auto stageB = [&](int c, us* Bd) {
    const int wq = wid - 4;
#pragma unroll
    for (int qq = 0; qq < 3; ++qq) {
      int G  = (wq * 3 + qq) * 64 + lane;
      int kk = G >> 7;
      int oo = G & 127;
      const us* src = Wt + (size_t)(bn * 128 + oo) * KTOT + kbase + c * 48 + kk * 8;
      async_copy16(src, Bd + (wq * 3 + qq) * 512);
    }
  };
  auto buildA = [&](float2 xv, us* Ad) {
    ull W[6];
    basis12(xv.x, W + 0);
    basis12(xv.y, W + 3);
    U2* p = reinterpret_cast<U2*>(Ad);
    const int g0 = (ai0 >> 1) * 3;
    U2 u0; u0.x = W[0]; u0.y = W[1];
    U2 u1; u1.x = W[2]; u1.y = W[3];
    U2 u2; u2.x = W[4]; u2.y = W[5];
    p[(g0 + 0) * 128 + ab] = u0;
    p[(g0 + 1) * 128 + ab] = u1;
    p[(g0 + 2) * 128 + ab] = u2;
  };

  float2 xa = make_float2(0.f, 0.f);
  if (builder) {
    float2 x0v = *reinterpret_cast<const float2*>(xrow);
    buildA(x0v, Acur);
    xa = *reinterpret_cast<const float2*>(xrow + 4);
  }
  if (stager) { stageB(0, Bcur); stageB(1, Bnxt); }
  asm volatile("s_waitcnt vmcnt(3) lgkmcnt(0)" ::: "memory");
  __builtin_amdgcn_s_barrier();

  for (int c = 0; c < 128; ++c) {
    int cf = (c + 2 < 128) ? (c + 2) : 127;
    float2 xb = xa;
    if (builder) {
      xb = *reinterpret_cast<const float2*>(xrow + cf * 4);
      buildA(xa, Aalt);
    }
    if (stager) stageB(cf, Bnn);
#pragma unroll
    for (int s = 0; s < 3; ++s) {
      const int kk = s * 2 + lh;
      bf16x8 a0 = *reinterpret_cast<const bf16x8*>(&Acur[(kk * 128 + wm + lo) * 8]);
      bf16x8 a1 = *reinterpret_cast<const bf16x8*>(&Acur[(kk * 128 + wm + 32 + lo) * 8]);
      bf16x8 b0 = *reinterpret_cast<const bf16x8*>(&Bcur[(kk * 128 + wn + lo) * 8]);
      acc[0] = __builtin_amdgcn_mfma_f32_32x32x16_bf16(a0, b0, acc[0], 0, 0, 0);
      acc[1] = __builtin_amdgcn_mfma_f32_32x32x16_bf16(a1, b0, acc[1], 0, 0, 0);
    }
    asm volatile("s_waitcnt vmcnt(3) lgkmcnt(0)" ::: "memory");
    __builtin_amdgcn_s_barrier();
    us* t = Bcur; Bcur = Bnxt; Bnxt = Bnn; Bnn = t;
    t = Acur; Acur = Aalt; Aalt = t;
    xa = xb;
  }
  asm volatile("s_waitcnt vmcnt(0) lgkmcnt(0)" ::: "memory");
#pragma unroll
  for (int mf = 0; mf < 2; ++mf)
#pragma unroll
    for (int r2 = 0; r2 < 16; ++r2) {
      int row = bm * 128 + wm + mf * 32 + (r2 & 3) + 8 * (r2 >> 2) + 4 * lh;
      atomicAdd(out + (size_t)row * OUTF + bn * 128 + wn + lo, acc[mf][r2]);
    }
}

// =============================================================================
extern "C" void kernel_launch(void* const* d_in, const int* in_sizes, int n_in,
                              void* d_out, int out_size, void* d_ws, size_t ws_size,
                              hipStream_t stream) {
  const float* x  = (const float*)d_in[0];   // [4096][1024]
  const float* bw = (const float*)d_in[1];   // [1024][1024]
  const float* sw = (const float*)d_in[2];   // [1024][1024][11]
  float* out = (float*)d_out;

  if (ws_size >= WTT_BYTES + P_BYTES) {
    us* WtT = (us*)d_ws;
    unsigned int* P = (unsigned int*)((char*)d_ws + WTT_BYTES);
    kan_build_wtT<<<2048, 256, 0, stream>>>(sw, bw, WtT);
    kan_gemm<<<512, THREADS, 0, stream>>>(x, WtT, P);
    kan_reduce4p<<<(int)(PQ_U32 / 4 / 256), 256, 0, stream>>>(
        out, (const uint4*)P);
  } else if (ws_size >= WTT_BYTES) {
    us* Wt = (us*)d_ws;
    kan_build_wt<<<(OUTF * INF) / 256, 256, 0, stream>>>(sw, bw, Wt);
    hipMemsetAsync(d_out, 0, OUT_BYTES, stream);
    kan_gemm_fb<<<512, 512, 0, stream>>>(x, Wt, out);
  }
}